// Round 1
// baseline (214.109 us; speedup 1.0000x reference)
//
#include <hip/hip_runtime.h>

#define LRC   0.01f
#define WCLIP 5.0f
#define LO   (-4.5951198501345898f)
#define HI   ( 4.5951198501345898f)

// ---------------------------------------------------------------------------
// K1: distances GEMM (4096x512 @ 512x256) -> idx[s][b]; plus logits transpose
//     blocks 0..255 : GEMM tiles 64x64, thread 4x4, BK=32, sequential-k fp32
//     blocks 256..319: transpose logits (1024x256) -> lT (256x1024)
// ---------------------------------------------------------------------------
__global__ __launch_bounds__(256) void k1_idx_lt(
    const float* __restrict__ cmap,    // (4096, 512)  = (SIZE*CMS, CTX)
    const float* __restrict__ ctx,     // (512, 256)
    const float* __restrict__ cbias,   // (4096)       = (SIZE*CMS)
    const float* __restrict__ logits,  // (1024, 256)
    int*   __restrict__ idxb,          // (1024, 256)
    float* __restrict__ lT)            // (256, 1024)
{
    __shared__ float smem[2 * 32 * 68];   // As[32][68] | Bs[32][68]  (= 64*68 for transpose)
    const int t   = threadIdx.x;
    const int blk = blockIdx.x;

    if (blk < 256) {
        float* As = smem;                // As[k][m], stride 68 (transposed A tile)
        float* Bs = smem + 32 * 68;      // Bs[k][n], stride 68
        const int gm = blk >> 2, gn = blk & 3;
        const int m0 = gm << 6, n0 = gn << 6;
        const int tm = t >> 4, tn = t & 15;

        float acc[4][4];
        #pragma unroll
        for (int i = 0; i < 4; i++)
            #pragma unroll
            for (int j = 0; j < 4; j++) acc[i][j] = 0.f;

        for (int k0 = 0; k0 < 512; k0 += 32) {
            // stage A tile (64 m-rows x 32 k), store transposed As[k][m]
            #pragma unroll
            for (int rep = 0; rep < 2; rep++) {
                int flat4 = rep * 256 + t;        // 0..511 float4s
                int r = flat4 >> 3;               // m-local 0..63
                int c = (flat4 & 7) << 2;         // k-local 0..28
                float4 v = *(const float4*)(cmap + (m0 + r) * 512 + k0 + c);
                As[(c + 0) * 68 + r] = v.x;
                As[(c + 1) * 68 + r] = v.y;
                As[(c + 2) * 68 + r] = v.z;
                As[(c + 3) * 68 + r] = v.w;
            }
            // stage B tile (32 k-rows x 64 n), natural Bs[k][n]
            #pragma unroll
            for (int rep = 0; rep < 2; rep++) {
                int flat4 = rep * 256 + t;
                int r = flat4 >> 4;               // k-local 0..31
                int c = (flat4 & 15) << 2;        // n-local 0..60
                *(float4*)(Bs + r * 68 + c) =
                    *(const float4*)(ctx + (k0 + r) * 256 + n0 + c);
            }
            __syncthreads();
            #pragma unroll 8
            for (int k = 0; k < 32; k++) {
                float4 a4 = *(const float4*)(As + k * 68 + (tm << 2));
                float4 b4 = *(const float4*)(Bs + k * 68 + (tn << 2));
                acc[0][0] = fmaf(a4.x, b4.x, acc[0][0]);
                acc[0][1] = fmaf(a4.x, b4.y, acc[0][1]);
                acc[0][2] = fmaf(a4.x, b4.z, acc[0][2]);
                acc[0][3] = fmaf(a4.x, b4.w, acc[0][3]);
                acc[1][0] = fmaf(a4.y, b4.x, acc[1][0]);
                acc[1][1] = fmaf(a4.y, b4.y, acc[1][1]);
                acc[1][2] = fmaf(a4.y, b4.z, acc[1][2]);
                acc[1][3] = fmaf(a4.y, b4.w, acc[1][3]);
                acc[2][0] = fmaf(a4.z, b4.x, acc[2][0]);
                acc[2][1] = fmaf(a4.z, b4.y, acc[2][1]);
                acc[2][2] = fmaf(a4.z, b4.z, acc[2][2]);
                acc[2][3] = fmaf(a4.z, b4.w, acc[2][3]);
                acc[3][0] = fmaf(a4.w, b4.x, acc[3][0]);
                acc[3][1] = fmaf(a4.w, b4.y, acc[3][1]);
                acc[3][2] = fmaf(a4.w, b4.z, acc[3][2]);
                acc[3][3] = fmaf(a4.w, b4.w, acc[3][3]);
            }
            __syncthreads();
        }
        // epilogue: thread's 4 rows are exactly neuron s's 4 context maps
        const int s = gm * 16 + tm;                  // m0 + tm*4 = s*4
        const float cb0 = cbias[s * 4 + 0];
        const float cb1 = cbias[s * 4 + 1];
        const float cb2 = cbias[s * 4 + 2];
        const float cb3 = cbias[s * 4 + 3];
        int4 iv;
        int* ivp = &iv.x;
        #pragma unroll
        for (int ni = 0; ni < 4; ni++) {
            int v = 0;
            v |= (acc[0][ni] > cb0) ? 1 : 0;
            v |= (acc[1][ni] > cb1) ? 2 : 0;
            v |= (acc[2][ni] > cb2) ? 4 : 0;
            v |= (acc[3][ni] > cb3) ? 8 : 0;
            ivp[ni] = v;
        }
        *(int4*)(idxb + s * 256 + n0 + (tn << 2)) = iv;
    } else {
        // transpose one 64(i) x 64(b) tile of logits into lT
        float* T = smem;                              // T[b_local][68]
        const int bi = blk - 256;
        const int i0 = (bi >> 2) << 6;
        const int b0 = (bi & 3) << 6;
        #pragma unroll
        for (int rep = 0; rep < 4; rep++) {
            int flat4 = rep * 256 + t;                // 0..1023
            int r = flat4 >> 4;                       // i-local
            int c = (flat4 & 15) << 2;                // b-local
            float4 v = *(const float4*)(logits + (i0 + r) * 256 + b0 + c);
            T[(c + 0) * 68 + r] = v.x;
            T[(c + 1) * 68 + r] = v.y;
            T[(c + 2) * 68 + r] = v.z;
            T[(c + 3) * 68 + r] = v.w;
        }
        __syncthreads();
        #pragma unroll
        for (int rep = 0; rep < 4; rep++) {
            int flat4 = rep * 256 + t;
            int r = flat4 >> 4;                       // b-local
            int c = (flat4 & 15) << 2;                // i-local
            *(float4*)(lT + (b0 + r) * 1024 + i0 + c) =
                *(const float4*)(T + r * 68 + c);
        }
    }
}

// ---------------------------------------------------------------------------
// K2: gathered forward dots + sigmoid + per-(s,j) last-b coefficient
//     grid 256 blocks x 512 thr; block = 4 neurons, thread = (i-half q, col b)
//     LDS stride 68: 68%32==4 -> balanced 8-lane bank groups (b128 floor)
// ---------------------------------------------------------------------------
__global__ __launch_bounds__(512) void k2_fwd(
    const float* __restrict__ logits,   // (1024, 256)
    const float* __restrict__ targets,  // (256)
    const float* __restrict__ weights,  // (1024, 16, 1024)
    const float* __restrict__ bias,     // (1)
    const int*   __restrict__ idxb,     // (1024, 256)
    float* __restrict__ outp,           // d_out first 1024*256
    float* __restrict__ coefb,          // (16384)
    int*   __restrict__ colb)           // (16384)
{
    __shared__ float wlds[64 * 68];     // 16 rows x 4 neurons, BI=64, pad->68
    __shared__ float sig_lds[4 * 256];
    __shared__ float red[4 * 256];
    __shared__ int   lastb[64];

    const int t  = threadIdx.x;
    const int q  = t >> 8;              // i-half
    const int b  = t & 255;             // batch column
    const int s0 = blockIdx.x << 2;

    if (t < 64) lastb[t] = -1;

    int jg[4], rowoff[4];
    #pragma unroll
    for (int g = 0; g < 4; g++) {
        jg[g] = idxb[(s0 + g) * 256 + b];
        rowoff[g] = ((g << 4) + jg[g]) * 68;
    }

    float acc[4] = {0.f, 0.f, 0.f, 0.f};
    const int iiBase = q << 5;

    for (int i0 = 0; i0 < 1024; i0 += 64) {
        // stage all 64 candidate rows' 64-wide i-slices (4 neurons x 16 rows)
        #pragma unroll
        for (int rep = 0; rep < 2; rep++) {
            int flat4 = rep * 512 + t;            // 0..1023 float4s
            int r = flat4 >> 4;                   // 0..63 = g*16+j
            int c = (flat4 & 15) << 2;            // 0..60
            int g = r >> 4, jj = r & 15;
            *(float4*)(wlds + r * 68 + c) =
                *(const float4*)(weights + (s0 + g) * 16384 + jj * 1024 + i0 + c);
        }
        __syncthreads();
        #pragma unroll
        for (int ii = 0; ii < 32; ii += 4) {
            const int i = i0 + iiBase + ii;
            float l0 = logits[(i + 0) * 256 + b];
            float l1 = logits[(i + 1) * 256 + b];
            float l2 = logits[(i + 2) * 256 + b];
            float l3 = logits[(i + 3) * 256 + b];
            #pragma unroll
            for (int g = 0; g < 4; g++) {
                float4 wv = *(const float4*)(wlds + rowoff[g] + iiBase + ii);
                acc[g] = fmaf(wv.x, l0, acc[g]);
                acc[g] = fmaf(wv.y, l1, acc[g]);
                acc[g] = fmaf(wv.z, l2, acc[g]);
                acc[g] = fmaf(wv.w, l3, acc[g]);
            }
        }
        __syncthreads();
    }

    // combine i-halves, clip, bias override, sigmoid
    if (q == 1) {
        #pragma unroll
        for (int g = 0; g < 4; g++) red[(g << 8) + b] = acc[g];
    }
    __syncthreads();
    if (q == 0) {
        #pragma unroll
        for (int g = 0; g < 4; g++) {
            float tot  = acc[g] + red[(g << 8) + b];
            float outv = fminf(fmaxf(tot, LO), HI);
            if (s0 + g == 0) outv = bias[0];      // neuron 0 forced to bias
            outp[(s0 + g) * 256 + b] = outv;
            sig_lds[(g << 8) + b] = 1.f / (1.f + __expf(-outv));
        }
    }
    __syncthreads();
    // last-b-wins per (neuron, weight-row): max over b with idx==j
    if (q == 0) {
        #pragma unroll
        for (int g = 0; g < 4; g++)
            atomicMax(&lastb[(g << 4) + jg[g]], b);
    }
    __syncthreads();
    if (t < 64) {
        int g  = t >> 4;
        int bb = lastb[t];
        float cf = 0.f;
        if (bb >= 0) cf = LRC * (sig_lds[(g << 8) + bb] - targets[bb]);
        coefb[(s0 << 4) + t] = cf;
        colb [(s0 << 4) + t] = bb;
    }
}

// ---------------------------------------------------------------------------
// K3: streaming weight update  new_w = clamp(w - coef * lT[b*], +-5)  (or copy)
//     grid 4096 blocks x 256 thr; 4 rows/block, float4 per thread per row
// ---------------------------------------------------------------------------
__global__ __launch_bounds__(256) void k3_update(
    const float* __restrict__ weights,
    const float* __restrict__ lT,
    const float* __restrict__ coefb,
    const int*   __restrict__ colb,
    float* __restrict__ outw)
{
    const int t  = threadIdx.x;
    const int r0 = blockIdx.x << 2;
    const int o  = t << 2;
    #pragma unroll
    for (int rr = 0; rr < 4; rr++) {
        const int row = r0 + rr;
        const int col = colb[row];        // uniform across block
        const float cf = coefb[row];
        float4 wv = *(const float4*)(weights + row * 1024 + o);
        float4 res;
        if (col >= 0) {
            float4 lv = *(const float4*)(lT + col * 1024 + o);
            res.x = fminf(fmaxf(wv.x - cf * lv.x, -WCLIP), WCLIP);
            res.y = fminf(fmaxf(wv.y - cf * lv.y, -WCLIP), WCLIP);
            res.z = fminf(fmaxf(wv.z - cf * lv.z, -WCLIP), WCLIP);
            res.w = fminf(fmaxf(wv.w - cf * lv.w, -WCLIP), WCLIP);
        } else {
            res = wv;                     // untouched row: verbatim copy, no clip
        }
        *(float4*)(outw + row * 1024 + o) = res;
    }
}

// ---------------------------------------------------------------------------
extern "C" void kernel_launch(void* const* d_in, const int* in_sizes, int n_in,
                              void* d_out, int out_size, void* d_ws, size_t ws_size,
                              hipStream_t stream) {
    const float* logits  = (const float*)d_in[0];   // (1024, 256)
    const float* ctx     = (const float*)d_in[1];   // (512, 256)
    const float* targets = (const float*)d_in[2];   // (256)
    const float* weights = (const float*)d_in[3];   // (1024, 16, 1024)
    const float* cmap    = (const float*)d_in[4];   // (1024, 4, 512)
    const float* cbias   = (const float*)d_in[5];   // (1024, 4, 1)
    const float* bias    = (const float*)d_in[6];   // (1)

    float* outp = (float*)d_out;                    // (1024, 256)
    float* outw = outp + 1024 * 256;                // (1024, 16, 1024)

    char* ws = (char*)d_ws;
    int*   idxb  = (int*)ws;                        // 1 MB   (1024x256 int)
    float* lT    = (float*)(ws + (1 << 20));        // 1 MB   (256x1024 f32)
    float* coefb = (float*)(ws + (2 << 20));        // 64 KB  (16384 f32)
    int*   colb  = (int*)  (ws + (2 << 20) + (1 << 16)); // 64 KB (16384 int)

    k1_idx_lt<<<320, 256, 0, stream>>>(cmap, ctx, cbias, logits, idxb, lT);
    k2_fwd  <<<256, 512, 0, stream>>>(logits, targets, weights, bias, idxb,
                                      outp, coefb, colb);
    k3_update<<<4096, 256, 0, stream>>>(weights, lT, coefb, colb, outw);
}